// Round 1
// baseline (699.201 us; speedup 1.0000x reference)
//
#include <hip/hip_runtime.h>
#include <hip/hip_bf16.h>

#define NN 10000
#define EE 320000
#define DD 128
#define TE 64   // edges (or nodes) per block tile

__device__ __forceinline__ float silu_f(float x) {
    return x / (1.0f + __expf(-x));
}
__device__ __forceinline__ float sigmoid_f(float x) {
    return 1.0f / (1.0f + __expf(-x));
}

__device__ __forceinline__ float atomic_add_f(float* p, float v) {
#if defined(__gfx90a__) || defined(__gfx940__) || defined(__gfx941__) || defined(__gfx942__) || defined(__gfx950__)
    return unsafeAtomicAdd(p, v);
#else
    return atomicAdd(p, v);
#endif
}

// acc[8][4] += S[el0..el0+7][:] @ W[128][128] restricted to cols c0..c0+3
__device__ __forceinline__ void gemm_acc(const float (*S)[DD],
                                         const float* __restrict__ W,
                                         int el0, int c0, float acc[8][4])
{
#pragma unroll 1
    for (int k = 0; k < DD; k += 4) {
        const float4 w0 = *(const float4*)&W[(k + 0) * DD + c0];
        const float4 w1 = *(const float4*)&W[(k + 1) * DD + c0];
        const float4 w2 = *(const float4*)&W[(k + 2) * DD + c0];
        const float4 w3 = *(const float4*)&W[(k + 3) * DD + c0];
#pragma unroll
        for (int i = 0; i < 8; ++i) {
            const float4 x = *(const float4*)&S[el0 + i][k];
            acc[i][0] = fmaf(x.w, w3.x, fmaf(x.z, w2.x, fmaf(x.y, w1.x, fmaf(x.x, w0.x, acc[i][0]))));
            acc[i][1] = fmaf(x.w, w3.y, fmaf(x.z, w2.y, fmaf(x.y, w1.y, fmaf(x.x, w0.y, acc[i][1]))));
            acc[i][2] = fmaf(x.w, w3.z, fmaf(x.z, w2.z, fmaf(x.y, w1.z, fmaf(x.x, w0.z, acc[i][2]))));
            acc[i][3] = fmaf(x.w, w3.w, fmaf(x.z, w2.w, fmaf(x.y, w1.w, fmaf(x.x, w0.w, acc[i][3]))));
        }
    }
}

__global__ __launch_bounds__(256, 2)
void edge_kernel(const float* __restrict__ h, const int* __restrict__ ei,
                 const float* __restrict__ coord,
                 const float* __restrict__ We1, const float* __restrict__ be1,
                 const float* __restrict__ We2, const float* __restrict__ be2,
                 const float* __restrict__ Wa, const float* __restrict__ ba,
                 const float* __restrict__ Wc1, const float* __restrict__ bc1,
                 const float* __restrict__ Wc2,
                 float* __restrict__ agg_h, float* __restrict__ agg_c,
                 float* __restrict__ cnt)
{
    __shared__ float sA[TE][DD];   // h[row] tile, then m1
    __shared__ float sB[TE][DD];   // h[col] tile, then edge_feat
    __shared__ float sRad[TE];
    __shared__ float sW[TE];
    __shared__ float sCd[TE][3];
    __shared__ int   sRow[TE];
    __shared__ int   sCol[TE];

    const int tid = threadIdx.x;
    const int e0g = blockIdx.x * TE;

    // ---- stage indices, coord diff, radial ----
    if (tid < TE) {
        const int e = e0g + tid;
        const int r = ei[e];
        const int c = ei[EE + e];
        sRow[tid] = r;
        sCol[tid] = c;
        const float dx = coord[r * 3 + 0] - coord[c * 3 + 0];
        const float dy = coord[r * 3 + 1] - coord[c * 3 + 1];
        const float dz = coord[r * 3 + 2] - coord[c * 3 + 2];
        sCd[tid][0] = dx; sCd[tid][1] = dy; sCd[tid][2] = dz;
        sRad[tid] = dx * dx + dy * dy + dz * dz;
    }
    __syncthreads();

    // ---- stage h[row], h[col]: one wave per edge, float2 per lane ----
    {
        const int wv = tid >> 6;
        const int ln = tid & 63;
        for (int el = wv; el < TE; el += 4) {
            const int r = sRow[el], c = sCol[el];
            const float2 vr = *(const float2*)&h[(size_t)r * DD + ln * 2];
            const float2 vc = *(const float2*)&h[(size_t)c * DD + ln * 2];
            *(float2*)&sA[el][ln * 2] = vr;
            *(float2*)&sB[el][ln * 2] = vc;
        }
    }
    __syncthreads();

    const int cg = tid & 31;         // col group: cols 4*cg .. 4*cg+3
    const int eg = tid >> 5;         // edge group: edges 8*eg .. 8*eg+7
    const int c0 = cg * 4;
    const int el0 = eg * 8;

    // ---- GEMM1: m1 = silu(h_r@W1a + h_c@W1b + radial*w1r + be1) ----
    float acc[8][4];
    {
        const float4 b  = *(const float4*)&be1[c0];
        const float4 wr = *(const float4*)&We1[256 * DD + c0];
#pragma unroll
        for (int i = 0; i < 8; ++i) {
            const float rad = sRad[el0 + i];
            acc[i][0] = fmaf(rad, wr.x, b.x);
            acc[i][1] = fmaf(rad, wr.y, b.y);
            acc[i][2] = fmaf(rad, wr.z, b.z);
            acc[i][3] = fmaf(rad, wr.w, b.w);
        }
    }
    gemm_acc(sA, We1, el0, c0, acc);                 // rows 0..127   (h[row])
    gemm_acc(sB, We1 + 128 * DD, el0, c0, acc);      // rows 128..255 (h[col])
    __syncthreads();
#pragma unroll
    for (int i = 0; i < 8; ++i) {
        sA[el0 + i][c0 + 0] = silu_f(acc[i][0]);
        sA[el0 + i][c0 + 1] = silu_f(acc[i][1]);
        sA[el0 + i][c0 + 2] = silu_f(acc[i][2]);
        sA[el0 + i][c0 + 3] = silu_f(acc[i][3]);
    }
    __syncthreads();

    // ---- GEMM2: m = silu(m1@We2 + be2) ----
    float m[8][4];
    {
        const float4 b = *(const float4*)&be2[c0];
#pragma unroll
        for (int i = 0; i < 8; ++i) { m[i][0] = b.x; m[i][1] = b.y; m[i][2] = b.z; m[i][3] = b.w; }
    }
    gemm_acc(sA, We2, el0, c0, m);
#pragma unroll
    for (int i = 0; i < 8; ++i) {
        m[i][0] = silu_f(m[i][0]); m[i][1] = silu_f(m[i][1]);
        m[i][2] = silu_f(m[i][2]); m[i][3] = silu_f(m[i][3]);
    }

    // ---- attention gate: att = sigmoid(m @ Wa + ba), reduce over cg lanes ----
    {
        const float4 wa = *(const float4*)&Wa[c0];
        float part[8];
#pragma unroll
        for (int i = 0; i < 8; ++i)
            part[i] = fmaf(m[i][3], wa.w, fmaf(m[i][2], wa.z, fmaf(m[i][1], wa.y, m[i][0] * wa.x)));
#pragma unroll
        for (int msk = 1; msk < 32; msk <<= 1) {
#pragma unroll
            for (int i = 0; i < 8; ++i) part[i] += __shfl_xor(part[i], msk);
        }
        const float ba0 = ba[0];
#pragma unroll
        for (int i = 0; i < 8; ++i) {
            const float att = sigmoid_f(part[i] + ba0);
            // edge_feat = m * att -> sB
            sB[el0 + i][c0 + 0] = m[i][0] * att;
            sB[el0 + i][c0 + 1] = m[i][1] * att;
            sB[el0 + i][c0 + 2] = m[i][2] * att;
            sB[el0 + i][c0 + 3] = m[i][3] * att;
        }
    }
    __syncthreads();

    // ---- coord gate: w = silu(edge_feat@Wc1 + bc1) @ Wc2 ----
    {
        float g[8][4];
        const float4 b = *(const float4*)&bc1[c0];
#pragma unroll
        for (int i = 0; i < 8; ++i) { g[i][0] = b.x; g[i][1] = b.y; g[i][2] = b.z; g[i][3] = b.w; }
        gemm_acc(sB, Wc1, el0, c0, g);
        const float4 wc2 = *(const float4*)&Wc2[c0];
        float part[8];
#pragma unroll
        for (int i = 0; i < 8; ++i) {
            part[i] = fmaf(silu_f(g[i][3]), wc2.w,
                      fmaf(silu_f(g[i][2]), wc2.z,
                      fmaf(silu_f(g[i][1]), wc2.y,
                           silu_f(g[i][0]) * wc2.x)));
        }
#pragma unroll
        for (int msk = 1; msk < 32; msk <<= 1) {
#pragma unroll
            for (int i = 0; i < 8; ++i) part[i] += __shfl_xor(part[i], msk);
        }
        if (cg == 0) {
#pragma unroll
            for (int i = 0; i < 8; ++i) sW[el0 + i] = part[i];
        }
    }
    __syncthreads();

    // ---- scatter: agg_h += edge_feat ; agg_c += coord_diff * w ; cnt += 1 ----
#pragma unroll 1
    for (int idx = tid; idx < TE * DD; idx += 256) {
        const int e = idx >> 7, k = idx & (DD - 1);
        atomic_add_f(&agg_h[(size_t)sRow[e] * DD + k], sB[e][k]);
    }
    if (tid < TE) {
        const int r = sRow[tid];
        const float w = sW[tid];
        atomic_add_f(&agg_c[r * 3 + 0], sCd[tid][0] * w);
        atomic_add_f(&agg_c[r * 3 + 1], sCd[tid][1] * w);
        atomic_add_f(&agg_c[r * 3 + 2], sCd[tid][2] * w);
        atomic_add_f(&cnt[r], 1.0f);
    }
}

__global__ __launch_bounds__(256, 2)
void node_kernel(const float* __restrict__ h, const float* __restrict__ coord,
                 const float* __restrict__ Wn1, const float* __restrict__ bn1,
                 const float* __restrict__ Wn2, const float* __restrict__ bn2,
                 const float* __restrict__ agg_h, const float* __restrict__ agg_c,
                 const float* __restrict__ cnt,
                 float* __restrict__ hout, float* __restrict__ cout)
{
    __shared__ float sA[TE][DD];   // h tile, then m
    __shared__ float sB[TE][DD];   // agg_h tile

    const int tid = threadIdx.x;
    const int n0 = blockIdx.x * TE;

    // ---- stage h and agg_h (coalesced float4) ----
#pragma unroll 1
    for (int idx = tid; idx < TE * DD / 4; idx += 256) {
        const int e = idx / (DD / 4), k4 = (idx % (DD / 4)) * 4;
        const int n = n0 + e;
        float4 v = make_float4(0.f, 0.f, 0.f, 0.f);
        float4 u = make_float4(0.f, 0.f, 0.f, 0.f);
        if (n < NN) {
            v = *(const float4*)&h[(size_t)n * DD + k4];
            u = *(const float4*)&agg_h[(size_t)n * DD + k4];
        }
        *(float4*)&sA[e][k4] = v;
        *(float4*)&sB[e][k4] = u;
    }
    __syncthreads();

    const int cg = tid & 31, eg = tid >> 5;
    const int c0 = cg * 4, el0 = eg * 8;

    // ---- layer 1: silu([h, agg_h] @ Wn1 + bn1) ----
    float acc[8][4];
    {
        const float4 b = *(const float4*)&bn1[c0];
#pragma unroll
        for (int i = 0; i < 8; ++i) { acc[i][0] = b.x; acc[i][1] = b.y; acc[i][2] = b.z; acc[i][3] = b.w; }
    }
    gemm_acc(sA, Wn1, el0, c0, acc);               // rows 0..127   (h)
    gemm_acc(sB, Wn1 + 128 * DD, el0, c0, acc);    // rows 128..255 (agg_h)
    __syncthreads();
#pragma unroll
    for (int i = 0; i < 8; ++i) {
        sA[el0 + i][c0 + 0] = silu_f(acc[i][0]);
        sA[el0 + i][c0 + 1] = silu_f(acc[i][1]);
        sA[el0 + i][c0 + 2] = silu_f(acc[i][2]);
        sA[el0 + i][c0 + 3] = silu_f(acc[i][3]);
    }
    __syncthreads();

    // ---- layer 2 + residual ----
    float o[8][4];
    {
        const float4 b = *(const float4*)&bn2[c0];
#pragma unroll
        for (int i = 0; i < 8; ++i) { o[i][0] = b.x; o[i][1] = b.y; o[i][2] = b.z; o[i][3] = b.w; }
    }
    gemm_acc(sA, Wn2, el0, c0, o);
#pragma unroll
    for (int i = 0; i < 8; ++i) {
        const int n = n0 + el0 + i;
        if (n < NN) {
            const float4 hv = *(const float4*)&h[(size_t)n * DD + c0];
            float4 r;
            r.x = hv.x + o[i][0]; r.y = hv.y + o[i][1];
            r.z = hv.z + o[i][2]; r.w = hv.w + o[i][3];
            *(float4*)&hout[(size_t)n * DD + c0] = r;
        }
    }

    // ---- coord out ----
    if (tid < TE * 3) {
        const int e = tid / 3, c = tid % 3;
        const int n = n0 + e;
        if (n < NN) {
            const float cn = fmaxf(cnt[n], 1.0f);
            cout[n * 3 + c] = coord[n * 3 + c] + agg_c[n * 3 + c] / cn;
        }
    }
}

extern "C" void kernel_launch(void* const* d_in, const int* in_sizes, int n_in,
                              void* d_out, int out_size, void* d_ws, size_t ws_size,
                              hipStream_t stream)
{
    const float* h     = (const float*)d_in[0];
    const int*   ei    = (const int*)  d_in[1];
    const float* coord = (const float*)d_in[2];
    const float* We1   = (const float*)d_in[3];
    const float* be1   = (const float*)d_in[4];
    const float* We2   = (const float*)d_in[5];
    const float* be2   = (const float*)d_in[6];
    const float* Wa    = (const float*)d_in[7];
    const float* ba    = (const float*)d_in[8];
    const float* Wn1   = (const float*)d_in[9];
    const float* bn1   = (const float*)d_in[10];
    const float* Wn2   = (const float*)d_in[11];
    const float* bn2   = (const float*)d_in[12];
    const float* Wc1   = (const float*)d_in[13];
    const float* bc1   = (const float*)d_in[14];
    const float* Wc2   = (const float*)d_in[15];

    float* agg_h = (float*)d_ws;            // N*D
    float* agg_c = agg_h + (size_t)NN * DD; // N*3
    float* cnt   = agg_c + (size_t)NN * 3;  // N

    (void)hipMemsetAsync(d_ws, 0, (size_t)(NN * DD + NN * 3 + NN) * sizeof(float), stream);

    edge_kernel<<<EE / TE, 256, 0, stream>>>(h, ei, coord, We1, be1, We2, be2,
                                             Wa, ba, Wc1, bc1, Wc2,
                                             agg_h, agg_c, cnt);

    float* hout = (float*)d_out;
    float* cout = hout + (size_t)NN * DD;
    node_kernel<<<(NN + TE - 1) / TE, 256, 0, stream>>>(h, coord, Wn1, bn1, Wn2, bn2,
                                                        agg_h, agg_c, cnt, hout, cout);
}

// Round 2
// 287.506 us; speedup vs baseline: 2.4320x; 2.4320x over previous
//
#include <hip/hip_runtime.h>
#include <hip/hip_bf16.h>

#define NN 10000
#define EE 320000
#define DD 128
#define TE 64   // edges (or nodes) per block tile

typedef __attribute__((ext_vector_type(8))) __bf16 bf16x8;
typedef __attribute__((ext_vector_type(4))) float  f32x4;

__device__ __forceinline__ float silu_f(float x) {
    return x / (1.0f + __expf(-x));
}
__device__ __forceinline__ float sigmoid_f(float x) {
    return 1.0f / (1.0f + __expf(-x));
}

__device__ __forceinline__ unsigned short f2bf(float f) {
    unsigned u = __builtin_bit_cast(unsigned, f);
    u += 0x7FFFu + ((u >> 16) & 1u);   // RNE
    return (unsigned short)(u >> 16);
}

__device__ __forceinline__ float atomic_add_f(float* p, float v) {
    return unsafeAtomicAdd(p, v);
}

// ---------------------------------------------------------------------------
// prep: convert + pack weights into per-lane MFMA B-fragments (bf16).
// Fragment (ct, ks): lane l holds B[k][n], n = ct*16+(l&15), k = ks*32+(l>>4)*8+j.
// Packed flat: region_base + ((ct*nks + ks)*64 + l)*8 + j
// Regions: pWe1 [0,32768) (K=256), pWe2 [32768,49152) (K=128), pWc1 [49152,65536)
// ---------------------------------------------------------------------------
__global__ void prep_kernel(const float* __restrict__ We1,
                            const float* __restrict__ We2,
                            const float* __restrict__ Wc1,
                            unsigned short* __restrict__ pW)
{
    const int idx = blockIdx.x * 256 + threadIdx.x;
    if (idx >= 65536) return;
    const float* src; int loc, nks;
    if (idx < 32768)      { src = We1; loc = idx;         nks = 8; }
    else if (idx < 49152) { src = We2; loc = idx - 32768; nks = 4; }
    else                  { src = Wc1; loc = idx - 49152; nks = 4; }
    const int per_ct = nks * 512;
    const int ct = loc / per_ct;
    const int r  = loc % per_ct;
    const int ks = r >> 9;
    const int r2 = r & 511;
    const int ln = r2 >> 3;
    const int j  = r2 & 7;
    const int k  = ks * 32 + (ln >> 4) * 8 + j;
    const int n  = ct * 16 + (ln & 15);
    pW[idx] = f2bf(src[k * DD + n]);
}

// ---------------------------------------------------------------------------
// edge kernel: 64 edges/block, 4 waves. MFMA 16x16x32 bf16.
// Wave w owns output cols [32w, 32w+32) (col-tiles ct = 2w, 2w+1), all 64 rows.
// ---------------------------------------------------------------------------
__global__ __launch_bounds__(256, 3)
void edge_kernel(const float* __restrict__ h, const int* __restrict__ ei,
                 const float* __restrict__ coord,
                 const float* __restrict__ We1, const float* __restrict__ be1,
                 const float* __restrict__ be2,
                 const float* __restrict__ Wa, const float* __restrict__ ba,
                 const float* __restrict__ bc1, const float* __restrict__ Wc2,
                 const unsigned short* __restrict__ pW,
                 float* __restrict__ agg_h, float* __restrict__ agg_c,
                 float* __restrict__ cnt)
{
    // A-tile buffer: GEMM1 view [64][256] bf16 (512 B rows); later reused:
    //   m1 view  = bytes [0, 16384),  [64][128] bf16 (256 B rows)
    //   ef view  = bytes [16384, 32768)
    __shared__ __align__(16) unsigned short sAbuf[64 * 256];
    __shared__ __align__(16) float sWred[4][64];
    __shared__ __align__(16) int   sRow[64];
    __shared__ int   sCol[64];
    __shared__ __align__(16) float sRad[64];
    __shared__ __align__(16) float sAtt[64];
    __shared__ float sCd[64][3];

    const int tid  = threadIdx.x;
    const int w    = tid >> 6;
    const int lane = tid & 63;
    const int g    = lane >> 4;      // k-group / row-subgroup
    const int l15  = lane & 15;
    const int e0g  = blockIdx.x * TE;

    char* const sAb = (char*)sAbuf;

    // ---- phase 0: indices, coord diff, radial ----
    if (tid < TE) {
        const int e = e0g + tid;
        const int r = ei[e];
        const int c = ei[EE + e];
        sRow[tid] = r; sCol[tid] = c;
        const float dx = coord[r * 3 + 0] - coord[c * 3 + 0];
        const float dy = coord[r * 3 + 1] - coord[c * 3 + 1];
        const float dz = coord[r * 3 + 2] - coord[c * 3 + 2];
        sCd[tid][0] = dx; sCd[tid][1] = dy; sCd[tid][2] = dz;
        sRad[tid] = dx * dx + dy * dy + dz * dz;
    }
    __syncthreads();

    // ---- phase 1: stage [h[row] | h[col]] as bf16 into swizzled A-tile ----
    // lanes 0-31: h[row] half (bytes 0-255), lanes 32-63: h[col] half (256-511)
    {
        const int halfsel = (lane >= 32) ? 1 : 0;
        const int bytec   = (lane & 31) * 8 + halfsel * 256;
#pragma unroll 4
        for (int s = 0; s < 16; ++s) {
            const int e = w * 16 + s;
            const int r = halfsel ? sCol[e] : sRow[e];
            const float4 v = *(const float4*)&h[(size_t)r * DD + (lane & 31) * 4];
            uint2 pk;
            pk.x = (unsigned)f2bf(v.x) | ((unsigned)f2bf(v.y) << 16);
            pk.y = (unsigned)f2bf(v.z) | ((unsigned)f2bf(v.w) << 16);
            *(uint2*)(sAb + e * 512 + (bytec ^ ((e & 7) << 4))) = pk;
        }
    }
    __syncthreads();

    f32x4 acc[4][2];

    // ---- phase 2: GEMM1  m1 = silu(A @ We1 + radial*wr + be1) ----
    {
        float be1c[2], wrc[2];
#pragma unroll
        for (int ctl = 0; ctl < 2; ++ctl) {
            const int col = w * 32 + ctl * 16 + l15;
            be1c[ctl] = be1[col];
            wrc[ctl]  = We1[256 * DD + col];
        }
#pragma unroll
        for (int rt = 0; rt < 4; ++rt) {
            const float4 rad4 = *(const float4*)&sRad[rt * 16 + g * 4];
            const float rr[4] = {rad4.x, rad4.y, rad4.z, rad4.w};
#pragma unroll
            for (int ctl = 0; ctl < 2; ++ctl)
#pragma unroll
                for (int j = 0; j < 4; ++j)
                    acc[rt][ctl][j] = fmaf(rr[j], wrc[ctl], be1c[ctl]);
        }
        const unsigned short* pWe1 = pW;
#pragma unroll 1
        for (int ks = 0; ks < 8; ++ks) {
            bf16x8 a[4];
#pragma unroll
            for (int rt = 0; rt < 4; ++rt) {
                const int row = rt * 16 + l15;
                const int byc = g * 16 + ks * 64;
                a[rt] = *(const bf16x8*)(sAb + row * 512 + (byc ^ ((row & 7) << 4)));
            }
            const bf16x8 b0 = *(const bf16x8*)&pWe1[(((2 * w + 0) * 8 + ks) * 64 + lane) * 8];
            const bf16x8 b1 = *(const bf16x8*)&pWe1[(((2 * w + 1) * 8 + ks) * 64 + lane) * 8];
#pragma unroll
            for (int rt = 0; rt < 4; ++rt) {
                acc[rt][0] = __builtin_amdgcn_mfma_f32_16x16x32_bf16(a[rt], b0, acc[rt][0], 0, 0, 0);
                acc[rt][1] = __builtin_amdgcn_mfma_f32_16x16x32_bf16(a[rt], b1, acc[rt][1], 0, 0, 0);
            }
        }
    }
    __syncthreads();   // GEMM1 tile reads done; safe to overwrite as m1 view

    // silu -> bf16 -> m1 view (256 B rows, same XOR swizzle)
#pragma unroll
    for (int rt = 0; rt < 4; ++rt)
#pragma unroll
        for (int ctl = 0; ctl < 2; ++ctl)
#pragma unroll
            for (int j = 0; j < 4; ++j) {
                const int row = rt * 16 + g * 4 + j;
                const int col = w * 32 + ctl * 16 + l15;
                *(unsigned short*)(sAb + row * 256 + ((col * 2) ^ ((row & 7) << 4)))
                    = f2bf(silu_f(acc[rt][ctl][j]));
            }
    __syncthreads();

    // ---- phase 3: GEMM2  m = silu(m1 @ We2 + be2) ----
    {
        float be2c[2];
#pragma unroll
        for (int ctl = 0; ctl < 2; ++ctl)
            be2c[ctl] = be2[w * 32 + ctl * 16 + l15];
#pragma unroll
        for (int rt = 0; rt < 4; ++rt)
#pragma unroll
            for (int ctl = 0; ctl < 2; ++ctl)
#pragma unroll
                for (int j = 0; j < 4; ++j)
                    acc[rt][ctl][j] = be2c[ctl];
        const unsigned short* pWe2 = pW + 32768;
#pragma unroll 1
        for (int ks = 0; ks < 4; ++ks) {
            bf16x8 a[4];
#pragma unroll
            for (int rt = 0; rt < 4; ++rt) {
                const int row = rt * 16 + l15;
                const int byc = g * 16 + ks * 64;
                a[rt] = *(const bf16x8*)(sAb + row * 256 + (byc ^ ((row & 7) << 4)));
            }
            const bf16x8 b0 = *(const bf16x8*)&pWe2[(((2 * w + 0) * 4 + ks) * 64 + lane) * 8];
            const bf16x8 b1 = *(const bf16x8*)&pWe2[(((2 * w + 1) * 4 + ks) * 64 + lane) * 8];
#pragma unroll
            for (int rt = 0; rt < 4; ++rt) {
                acc[rt][0] = __builtin_amdgcn_mfma_f32_16x16x32_bf16(a[rt], b0, acc[rt][0], 0, 0, 0);
                acc[rt][1] = __builtin_amdgcn_mfma_f32_16x16x32_bf16(a[rt], b1, acc[rt][1], 0, 0, 0);
            }
        }
    }
    // silu in place: acc now holds m
#pragma unroll
    for (int rt = 0; rt < 4; ++rt)
#pragma unroll
        for (int ctl = 0; ctl < 2; ++ctl)
#pragma unroll
            for (int j = 0; j < 4; ++j)
                acc[rt][ctl][j] = silu_f(acc[rt][ctl][j]);

    // ---- attention partial: att = sigmoid(sum_col m*Wa + ba) ----
    {
        float wac[2];
#pragma unroll
        for (int ctl = 0; ctl < 2; ++ctl)
            wac[ctl] = Wa[w * 32 + ctl * 16 + l15];
        float part[4][4];
#pragma unroll
        for (int rt = 0; rt < 4; ++rt)
#pragma unroll
            for (int j = 0; j < 4; ++j)
                part[rt][j] = fmaf(acc[rt][0][j], wac[0], acc[rt][1][j] * wac[1]);
#pragma unroll
        for (int msk = 1; msk < 16; msk <<= 1)
#pragma unroll
            for (int rt = 0; rt < 4; ++rt)
#pragma unroll
                for (int j = 0; j < 4; ++j)
                    part[rt][j] += __shfl_xor(part[rt][j], msk);
        if (l15 == 0) {
#pragma unroll
            for (int rt = 0; rt < 4; ++rt) {
                float4 p4 = make_float4(part[rt][0], part[rt][1], part[rt][2], part[rt][3]);
                *(float4*)&sWred[w][rt * 16 + g * 4] = p4;
            }
        }
    }
    __syncthreads();
    if (tid < TE) {
        const float s = sWred[0][tid] + sWred[1][tid] + sWred[2][tid] + sWred[3][tid];
        sAtt[tid] = sigmoid_f(s + ba[0]);
    }
    __syncthreads();

    // ---- phase 4: edge_feat = m*att -> ef view (bf16) + agg_h atomics ----
    char* const efb = sAb + 16384;
#pragma unroll
    for (int rt = 0; rt < 4; ++rt) {
        const float4 a4 = *(const float4*)&sAtt[rt * 16 + g * 4];
        const int4  rr = *(const int4*)&sRow[rt * 16 + g * 4];
        const float at[4] = {a4.x, a4.y, a4.z, a4.w};
        const int   ri[4] = {rr.x, rr.y, rr.z, rr.w};
#pragma unroll
        for (int ctl = 0; ctl < 2; ++ctl) {
            const int col = w * 32 + ctl * 16 + l15;
#pragma unroll
            for (int j = 0; j < 4; ++j) {
                const float v = acc[rt][ctl][j] * at[j];
                acc[rt][ctl][j] = v;
                const int row = rt * 16 + g * 4 + j;
                *(unsigned short*)(efb + row * 256 + ((col * 2) ^ ((row & 7) << 4))) = f2bf(v);
                atomic_add_f(&agg_h[(size_t)ri[j] * DD + col], v);
            }
        }
    }
    __syncthreads();

    // ---- phase 5: GEMMc  w = (silu(ef @ Wc1 + bc1)) @ Wc2 ----
    {
        float bc1c[2];
#pragma unroll
        for (int ctl = 0; ctl < 2; ++ctl)
            bc1c[ctl] = bc1[w * 32 + ctl * 16 + l15];
#pragma unroll
        for (int rt = 0; rt < 4; ++rt)
#pragma unroll
            for (int ctl = 0; ctl < 2; ++ctl)
#pragma unroll
                for (int j = 0; j < 4; ++j)
                    acc[rt][ctl][j] = bc1c[ctl];
        const unsigned short* pWc1 = pW + 49152;
#pragma unroll 1
        for (int ks = 0; ks < 4; ++ks) {
            bf16x8 a[4];
#pragma unroll
            for (int rt = 0; rt < 4; ++rt) {
                const int row = rt * 16 + l15;
                const int byc = g * 16 + ks * 64;
                a[rt] = *(const bf16x8*)(efb + row * 256 + (byc ^ ((row & 7) << 4)));
            }
            const bf16x8 b0 = *(const bf16x8*)&pWc1[(((2 * w + 0) * 4 + ks) * 64 + lane) * 8];
            const bf16x8 b1 = *(const bf16x8*)&pWc1[(((2 * w + 1) * 4 + ks) * 64 + lane) * 8];
#pragma unroll
            for (int rt = 0; rt < 4; ++rt) {
                acc[rt][0] = __builtin_amdgcn_mfma_f32_16x16x32_bf16(a[rt], b0, acc[rt][0], 0, 0, 0);
                acc[rt][1] = __builtin_amdgcn_mfma_f32_16x16x32_bf16(a[rt], b1, acc[rt][1], 0, 0, 0);
            }
        }
        float wcc[2];
#pragma unroll
        for (int ctl = 0; ctl < 2; ++ctl)
            wcc[ctl] = Wc2[w * 32 + ctl * 16 + l15];
        float part[4][4];
#pragma unroll
        for (int rt = 0; rt < 4; ++rt)
#pragma unroll
            for (int j = 0; j < 4; ++j)
                part[rt][j] = fmaf(silu_f(acc[rt][0][j]), wcc[0], silu_f(acc[rt][1][j]) * wcc[1]);
#pragma unroll
        for (int msk = 1; msk < 16; msk <<= 1)
#pragma unroll
            for (int rt = 0; rt < 4; ++rt)
#pragma unroll
                for (int j = 0; j < 4; ++j)
                    part[rt][j] += __shfl_xor(part[rt][j], msk);
        if (l15 == 0) {
#pragma unroll
            for (int rt = 0; rt < 4; ++rt) {
                float4 p4 = make_float4(part[rt][0], part[rt][1], part[rt][2], part[rt][3]);
                *(float4*)&sWred[w][rt * 16 + g * 4] = p4;
            }
        }
    }
    __syncthreads();

    // ---- phase 6: coord scatter (per edge) ----
    if (tid < TE) {
        const float wv = sWred[0][tid] + sWred[1][tid] + sWred[2][tid] + sWred[3][tid];
        const int r = sRow[tid];
        atomic_add_f(&agg_c[r * 3 + 0], sCd[tid][0] * wv);
        atomic_add_f(&agg_c[r * 3 + 1], sCd[tid][1] * wv);
        atomic_add_f(&agg_c[r * 3 + 2], sCd[tid][2] * wv);
        atomic_add_f(&cnt[r], 1.0f);
    }
}

// ---------------------------------------------------------------------------
// node kernel (fp32, unchanged from round 0)
// ---------------------------------------------------------------------------
__device__ __forceinline__ void gemm_acc(const float (*S)[DD],
                                         const float* __restrict__ W,
                                         int el0, int c0, float acc[8][4])
{
#pragma unroll 1
    for (int k = 0; k < DD; k += 4) {
        const float4 w0 = *(const float4*)&W[(k + 0) * DD + c0];
        const float4 w1 = *(const float4*)&W[(k + 1) * DD + c0];
        const float4 w2 = *(const float4*)&W[(k + 2) * DD + c0];
        const float4 w3 = *(const float4*)&W[(k + 3) * DD + c0];
#pragma unroll
        for (int i = 0; i < 8; ++i) {
            const float4 x = *(const float4*)&S[el0 + i][k];
            acc[i][0] = fmaf(x.w, w3.x, fmaf(x.z, w2.x, fmaf(x.y, w1.x, fmaf(x.x, w0.x, acc[i][0]))));
            acc[i][1] = fmaf(x.w, w3.y, fmaf(x.z, w2.y, fmaf(x.y, w1.y, fmaf(x.x, w0.y, acc[i][1]))));
            acc[i][2] = fmaf(x.w, w3.z, fmaf(x.z, w2.z, fmaf(x.y, w1.z, fmaf(x.x, w0.z, acc[i][2]))));
            acc[i][3] = fmaf(x.w, w3.w, fmaf(x.z, w2.w, fmaf(x.y, w1.w, fmaf(x.x, w0.w, acc[i][3]))));
        }
    }
}

__global__ __launch_bounds__(256, 2)
void node_kernel(const float* __restrict__ h, const float* __restrict__ coord,
                 const float* __restrict__ Wn1, const float* __restrict__ bn1,
                 const float* __restrict__ Wn2, const float* __restrict__ bn2,
                 const float* __restrict__ agg_h, const float* __restrict__ agg_c,
                 const float* __restrict__ cnt,
                 float* __restrict__ hout, float* __restrict__ cout)
{
    __shared__ float sA[TE][DD];
    __shared__ float sB[TE][DD];

    const int tid = threadIdx.x;
    const int n0 = blockIdx.x * TE;

#pragma unroll 1
    for (int idx = tid; idx < TE * DD / 4; idx += 256) {
        const int e = idx / (DD / 4), k4 = (idx % (DD / 4)) * 4;
        const int n = n0 + e;
        float4 v = make_float4(0.f, 0.f, 0.f, 0.f);
        float4 u = make_float4(0.f, 0.f, 0.f, 0.f);
        if (n < NN) {
            v = *(const float4*)&h[(size_t)n * DD + k4];
            u = *(const float4*)&agg_h[(size_t)n * DD + k4];
        }
        *(float4*)&sA[e][k4] = v;
        *(float4*)&sB[e][k4] = u;
    }
    __syncthreads();

    const int cg = tid & 31, eg = tid >> 5;
    const int c0 = cg * 4, el0 = eg * 8;

    float acc[8][4];
    {
        const float4 b = *(const float4*)&bn1[c0];
#pragma unroll
        for (int i = 0; i < 8; ++i) { acc[i][0] = b.x; acc[i][1] = b.y; acc[i][2] = b.z; acc[i][3] = b.w; }
    }
    gemm_acc(sA, Wn1, el0, c0, acc);
    gemm_acc(sB, Wn1 + 128 * DD, el0, c0, acc);
    __syncthreads();
#pragma unroll
    for (int i = 0; i < 8; ++i) {
        sA[el0 + i][c0 + 0] = silu_f(acc[i][0]);
        sA[el0 + i][c0 + 1] = silu_f(acc[i][1]);
        sA[el0 + i][c0 + 2] = silu_f(acc[i][2]);
        sA[el0 + i][c0 + 3] = silu_f(acc[i][3]);
    }
    __syncthreads();

    float o[8][4];
    {
        const float4 b = *(const float4*)&bn2[c0];
#pragma unroll
        for (int i = 0; i < 8; ++i) { o[i][0] = b.x; o[i][1] = b.y; o[i][2] = b.z; o[i][3] = b.w; }
    }
    gemm_acc(sA, Wn2, el0, c0, o);
#pragma unroll
    for (int i = 0; i < 8; ++i) {
        const int n = n0 + el0 + i;
        if (n < NN) {
            const float4 hv = *(const float4*)&h[(size_t)n * DD + c0];
            float4 r;
            r.x = hv.x + o[i][0]; r.y = hv.y + o[i][1];
            r.z = hv.z + o[i][2]; r.w = hv.w + o[i][3];
            *(float4*)&hout[(size_t)n * DD + c0] = r;
        }
    }

    if (tid < TE * 3) {
        const int e = tid / 3, c = tid % 3;
        const int n = n0 + e;
        if (n < NN) {
            const float cn = fmaxf(cnt[n], 1.0f);
            cout[n * 3 + c] = coord[n * 3 + c] + agg_c[n * 3 + c] / cn;
        }
    }
}

extern "C" void kernel_launch(void* const* d_in, const int* in_sizes, int n_in,
                              void* d_out, int out_size, void* d_ws, size_t ws_size,
                              hipStream_t stream)
{
    const float* h     = (const float*)d_in[0];
    const int*   ei    = (const int*)  d_in[1];
    const float* coord = (const float*)d_in[2];
    const float* We1   = (const float*)d_in[3];
    const float* be1   = (const float*)d_in[4];
    const float* We2   = (const float*)d_in[5];
    const float* be2   = (const float*)d_in[6];
    const float* Wa    = (const float*)d_in[7];
    const float* ba    = (const float*)d_in[8];
    const float* Wn1   = (const float*)d_in[9];
    const float* bn1   = (const float*)d_in[10];
    const float* Wn2   = (const float*)d_in[11];
    const float* bn2   = (const float*)d_in[12];
    const float* Wc1   = (const float*)d_in[13];
    const float* bc1   = (const float*)d_in[14];
    const float* Wc2   = (const float*)d_in[15];

    float* agg_h = (float*)d_ws;                 // N*D
    float* agg_c = agg_h + (size_t)NN * DD;      // N*3
    float* cnt   = agg_c + (size_t)NN * 3;       // N
    unsigned short* pW = (unsigned short*)(cnt + NN);   // 65536 bf16

    (void)hipMemsetAsync(d_ws, 0, (size_t)(NN * DD + NN * 3 + NN) * sizeof(float), stream);

    prep_kernel<<<256, 256, 0, stream>>>(We1, We2, Wc1, pW);

    edge_kernel<<<EE / TE, 256, 0, stream>>>(h, ei, coord, We1, be1, be2,
                                             Wa, ba, bc1, Wc2, pW,
                                             agg_h, agg_c, cnt);

    float* hout = (float*)d_out;
    float* cout = hout + (size_t)NN * DD;
    node_kernel<<<(NN + TE - 1) / TE, 256, 0, stream>>>(h, coord, Wn1, bn1, Wn2, bn2,
                                                        agg_h, agg_c, cnt, hout, cout);
}